// Round 16
// baseline (271.046 us; speedup 1.0000x reference)
//
#include <hip/hip_runtime.h>
#include <hip/hip_bf16.h>

// Problem constants: B=4, S=1024, D=1024, H=16, DK=DV=64
// Output 0: out [B,S,D] f32. Output 1: attn [B,H,S,S] f32 (268 MB!).
// Softmax over QUERY axis: attn[b,h,q,k] = exp(s[q,k]) / sum_q' exp(s[q',k]).
//
// R16 = R13 exactly (best known 216.07us; R15's T14 split reverted as
// neutral) + __launch_bounds__(256, 8) on k_colsum/k_attn to force <=64 VGPR
// (they sat at 72 -> 4 waves/SIMD per the 64/128/256 occupancy cliffs;
// <=64 unlocks 8 waves/SIMD for these latency-bound kernels).

typedef __bf16 bf16;
typedef bf16 bf16x4 __attribute__((ext_vector_type(4)));
typedef bf16 bf16x8 __attribute__((ext_vector_type(8)));
typedef float f32x4 __attribute__((ext_vector_type(4)));
typedef unsigned char u8x16 __attribute__((ext_vector_type(16)));

#define MFMA(a, b, c) __builtin_amdgcn_mfma_f32_16x16x32_bf16((a), (b), (c), 0, 0, 0)

__device__ __forceinline__ bf16 f2b(float x) { return (bf16)x; }

__device__ __forceinline__ void gl_lds16(const bf16* g, void* l) {
    __builtin_amdgcn_global_load_lds(
        (const __attribute__((address_space(1))) void*)g,
        (__attribute__((address_space(3))) void*)l, 16, 0, 0);
}

// Wait own-wave LDS ops only (no cross-wave barrier, no vmem drain).
__device__ __forceinline__ void wait_lgkm() {
    __builtin_amdgcn_sched_barrier(0);
    asm volatile("s_waitcnt lgkmcnt(0)" ::: "memory");
    __builtin_amdgcn_sched_barrier(0);
}

__device__ __forceinline__ void bar_fenced() {
    __builtin_amdgcn_sched_barrier(0);
    __builtin_amdgcn_s_barrier();
    __builtin_amdgcn_sched_barrier(0);
}

// ---------------------------------------------------------------------------
// Fused pre-pass. y=0..2: Q/K/V f32->bf16 (Q scaled 1/8, exact pow2).
// y=3..6: weight transpose W f32 [K][N] -> WT bf16 [N][K].
// ---------------------------------------------------------------------------
__global__ __launch_bounds__(256) void k_pre(
    const float* __restrict__ Q, const float* __restrict__ K, const float* __restrict__ V,
    const float* __restrict__ W0, const float* __restrict__ W1,
    const float* __restrict__ W2, const float* __restrict__ W3,
    bf16* __restrict__ Qb, bf16* __restrict__ Kb, bf16* __restrict__ Vb,
    bf16* __restrict__ T0, bf16* __restrict__ T1,
    bf16* __restrict__ T2, bf16* __restrict__ T3)
{
    const int z = blockIdx.y;
    __shared__ float tile[32][33];
    if (z < 3) {
        const float* src = z == 0 ? Q : z == 1 ? K : V;
        bf16* dst = z == 0 ? Qb : z == 1 ? Kb : Vb;
        const float sc = z == 0 ? 0.125f : 1.0f;
        size_t idx = ((size_t)blockIdx.x * 256 + threadIdx.x) * 8;
        const size_t stride = (size_t)gridDim.x * 2048;
        for (; idx < 4194304; idx += stride) {
            const float4 v0 = *(const float4*)(src + idx);
            const float4 v1 = *(const float4*)(src + idx + 4);
            bf16x8 o = { f2b(v0.x * sc), f2b(v0.y * sc), f2b(v0.z * sc), f2b(v0.w * sc),
                         f2b(v1.x * sc), f2b(v1.y * sc), f2b(v1.z * sc), f2b(v1.w * sc) };
            *(bf16x8*)(dst + idx) = o;
        }
    } else {
        const int zz = z - 3;
        const float* W = zz == 0 ? W0 : zz == 1 ? W1 : zz == 2 ? W2 : W3;
        bf16*        T = zz == 0 ? T0 : zz == 1 ? T1 : zz == 2 ? T2 : T3;
        const int bx = blockIdx.x & 31, by = blockIdx.x >> 5;
        const int t = threadIdx.x;
        const int r = t >> 3, c = (t & 7) * 4;
        {
            const float4 v = *(const float4*)(W + (size_t)(by * 32 + r) * 1024 + bx * 32 + c);
            tile[r][c + 0] = v.x; tile[r][c + 1] = v.y; tile[r][c + 2] = v.z; tile[r][c + 3] = v.w;
        }
        __syncthreads();
        bf16x4 o = { f2b(tile[c + 0][r]), f2b(tile[c + 1][r]), f2b(tile[c + 2][r]), f2b(tile[c + 3][r]) };
        *(bf16x4*)(T + (size_t)(bx * 32 + r) * 1024 + by * 32 + c) = o;
    }
}

// ---------------------------------------------------------------------------
// Projection GEMM: BM=64, BN=128, BK=64. grid (8, 64, 3) = 1536 blocks (6/CU).
// ---------------------------------------------------------------------------
__global__ __launch_bounds__(256) void k_proj(
    const bf16* __restrict__ Xq, const bf16* __restrict__ Xk, const bf16* __restrict__ Xv,
    const bf16* __restrict__ WTq, const bf16* __restrict__ WTk, const bf16* __restrict__ WTv,
    bf16* __restrict__ qh, bf16* __restrict__ kh, bf16* __restrict__ vTh)
{
    const int z = blockIdx.z;
    const bf16* X  = z == 0 ? Xq : z == 1 ? Xk : Xv;
    const bf16* WT = z == 0 ? WTq : z == 1 ? WTk : WTv;

    __shared__ char AsB[8192];    // [64 rows][64 k] bf16, source-swizzled
    __shared__ char BsB[16384];   // [128 rows][64 k]

    const int tid = threadIdx.x;
    const int lane = tid & 63, w = tid >> 6;
    const int lr = lane & 15, lg = lane >> 4;
    const int wm = w >> 1, wn = w & 1;
    const int m0 = blockIdx.y * 64, n0 = blockIdx.x * 128;

    const int lrow = lane >> 3;
    const int swz8 = ((lane & 7) ^ lrow) * 8;
    const bf16* Ab = X  + (size_t)(m0 + w * 8 + lrow) * 1024 + swz8;
    const bf16* Bb = WT + (size_t)(n0 + w * 8 + lrow) * 1024 + swz8;
    char* Alb = AsB + w * 1024;
    char* Blb = BsB + w * 1024;

    f32x4 acc[2][4] = {};

    for (int k0 = 0; k0 < 1024; k0 += 64) {
        gl_lds16(Ab + k0,          Alb);
        gl_lds16(Ab + 32768 + k0,  Alb + 4096);
        #pragma unroll
        for (int i = 0; i < 4; ++i)
            gl_lds16(Bb + (size_t)i * 32768 + k0, Blb + i * 4096);
        __syncthreads();
        #pragma unroll
        for (int ks = 0; ks < 2; ++ks) {
            const int swr = ((ks * 4 + lg) ^ (lr & 7)) << 4;
            bf16x8 a[2], bb[4];
            #pragma unroll
            for (int fm = 0; fm < 2; ++fm)
                a[fm] = *(const bf16x8*)(AsB + (wm * 32 + fm * 16 + lr) * 128 + swr);
            #pragma unroll
            for (int fn = 0; fn < 4; ++fn)
                bb[fn] = *(const bf16x8*)(BsB + (wn * 64 + fn * 16 + lr) * 128 + swr);
            #pragma unroll
            for (int fm = 0; fm < 2; ++fm)
                #pragma unroll
                for (int fn = 0; fn < 4; ++fn)
                    acc[fm][fn] = MFMA(a[fm], bb[fn], acc[fm][fn]);
        }
        __syncthreads();
    }

    if (z < 2) {
        bf16* dst = (z == 0) ? qh : kh;
        #pragma unroll
        for (int fm = 0; fm < 2; ++fm)
            #pragma unroll
            for (int fn = 0; fn < 4; ++fn)
                #pragma unroll
                for (int r = 0; r < 4; ++r) {
                    const int m = m0 + wm * 32 + fm * 16 + lg * 4 + r;
                    const int n = n0 + wn * 64 + fn * 16 + lr;
                    const int b = m >> 10, s = m & 1023, h = n >> 6, d = n & 63;
                    dst[(((size_t)(b * 16 + h)) * 1024 + s) * 64 + d] = f2b(acc[fm][fn][r]);
                }
    } else {
        #pragma unroll
        for (int fm = 0; fm < 2; ++fm)
            #pragma unroll
            for (int fn = 0; fn < 4; ++fn) {
                const int m = m0 + wm * 32 + fm * 16 + lg * 4;
                const int n = n0 + wn * 64 + fn * 16 + lr;
                const int b = m >> 10, s = m & 1023, h = n >> 6, d = n & 63;
                bf16x4 o = { f2b(acc[fm][fn][0]), f2b(acc[fm][fn][1]),
                             f2b(acc[fm][fn][2]), f2b(acc[fm][fn][3]) };
                *(bf16x4*)&vTh[(((size_t)(b * 16 + h)) * 64 + d) * 1024 + s] = o;
            }
    }
}

// ---------------------------------------------------------------------------
// Column softmax partial sums, 2-way q-split: csp[half][bh][k]. Grid 4096.
// __launch_bounds__(256,8): force <=64 VGPR -> 8 waves/SIMD.
// ---------------------------------------------------------------------------
__global__ __launch_bounds__(256, 8) void k_colsum(
    const bf16* __restrict__ qh, const bf16* __restrict__ kh,
    const unsigned char* __restrict__ mask, float* __restrict__ csp)
{
    const int bid = blockIdx.x;
    const int wg = (bid & 7) * 512 + (bid >> 3);   // XCD-chunked (4096 % 8 == 0)
    const int bh = wg >> 6;
    const int t6 = wg & 63;
    const int kk0 = (t6 >> 1) * 32;
    const int half = t6 & 1;
    const int qbase = half * 512;
    const int b = bh >> 4;
    const bf16* qb = qh + (size_t)bh * 65536;
    const bf16* kb = kh + (size_t)bh * 65536;
    const unsigned char* mb = mask + (size_t)b * 1048576;

    const int tid = threadIdx.x;
    const int lane = tid & 63, w = tid >> 6;
    const int lr = lane & 15, lg = lane >> 4;

    __shared__ unsigned char Ml[2][128 * 48];   // rows wave-private (w*32..+31)
    __shared__ float csum[4][32];

    const int mrow = tid >> 1, mcoff = (tid & 1) * 16;

    bf16x8 bfr[2][2];
    #pragma unroll
    for (int fn = 0; fn < 2; ++fn)
        #pragma unroll
        for (int ks = 0; ks < 2; ++ks)
            bfr[fn][ks] = *(const bf16x8*)(kb + (size_t)(kk0 + fn * 16 + lr) * 64 + ks * 32 + lg * 8);

    *(u8x16*)&Ml[0][mrow * 48 + mcoff] =
        *(const u8x16*)(mb + (size_t)(qbase + mrow) * 1024 + kk0 + mcoff);
    wait_lgkm();

    float colacc[2][4] = {};

    #pragma unroll
    for (int qt = 0; qt < 4; ++qt) {
        const int q0 = qbase + qt * 128;
        const int cur = qt & 1;
        if (qt < 3)
            *(u8x16*)&Ml[cur ^ 1][mrow * 48 + mcoff] =
                *(const u8x16*)(mb + (size_t)(q0 + 128 + mrow) * 1024 + kk0 + mcoff);

        bf16x8 a[2][2];
        #pragma unroll
        for (int fm = 0; fm < 2; ++fm) {
            const int q = q0 + w * 32 + fm * 16 + lr;
            a[fm][0] = *(const bf16x8*)(qb + (size_t)q * 64 + lg * 8);
            a[fm][1] = *(const bf16x8*)(qb + (size_t)q * 64 + 32 + lg * 8);
        }

        #pragma unroll
        for (int fm = 0; fm < 2; ++fm) {
            const int ql = w * 32 + fm * 16 + lr;
            #pragma unroll
            for (int fn = 0; fn < 2; ++fn) {
                f32x4 c = {0.f, 0.f, 0.f, 0.f};
                c = MFMA(bfr[fn][0], a[fm][0], c);
                c = MFMA(bfr[fn][1], a[fm][1], c);
                const unsigned int m4 = *(const unsigned int*)&Ml[cur][ql * 48 + fn * 16 + lg * 4];
                #pragma unroll
                for (int r = 0; r < 4; ++r)
                    colacc[fn][r] += ((m4 >> (8 * r)) & 255u) ? 0.f : __expf(c[r]);
            }
        }
        wait_lgkm();
    }

    #pragma unroll
    for (int fn = 0; fn < 2; ++fn)
        #pragma unroll
        for (int r = 0; r < 4; ++r) {
            float v = colacc[fn][r];
            v += __shfl_xor(v, 1);
            v += __shfl_xor(v, 2);
            v += __shfl_xor(v, 4);
            v += __shfl_xor(v, 8);
            if (lr == 0) csum[w][fn * 16 + lg * 4 + r] = v;
        }
    __syncthreads();
    if (tid < 32) {
        const float s = csum[0][tid] + csum[1][tid] + csum[2][tid] + csum[3][tid];
        csp[(size_t)half * 65536 + (size_t)bh * 1024 + kk0 + tid] = s;
    }
}

// ---------------------------------------------------------------------------
// Fused attn: QBLK=32, 1-D grid 2048 XCD-chunked, 4 waves, barrier-free loop.
// __launch_bounds__(256,8): force <=64 VGPR. linv = rcp(csp[0]+csp[1]).
// NT attn stores from LDS (full 128B lines).
// ---------------------------------------------------------------------------
__global__ __launch_bounds__(256, 8) void k_attn(
    const bf16* __restrict__ qh, const bf16* __restrict__ kh, const bf16* __restrict__ vTh,
    const unsigned char* __restrict__ mask, const float* __restrict__ csp,
    float* __restrict__ attn_out, bf16* __restrict__ attn_head)
{
    const int bid = blockIdx.x;
    const int wg = (bid & 7) * 256 + (bid >> 3);   // XCD-chunked
    const int bh = wg >> 5;
    const int q0 = (wg & 31) * 32;
    const int b = bh >> 4, h = bh & 15;
    const bf16* qb = qh + (size_t)bh * 65536;
    const bf16* kb = kh + (size_t)bh * 65536;
    const bf16* vb = vTh + (size_t)bh * 65536;
    const unsigned char* mb = mask + (size_t)b * 1048576 + (size_t)q0 * 1024;
    const float* c0 = csp + (size_t)bh * 1024;
    const float* c1 = csp + 65536 + (size_t)bh * 1024;

    const int tid = threadIdx.x;
    const int lane = tid & 63, w = tid >> 6;
    const int lr = lane & 15, lg = lane >> 4;

    __shared__ __align__(16) char smem[17408 + 8192];
    bf16* Pl = (bf16*)smem;
    unsigned char* Mw = (unsigned char*)(smem + 17408) + w * 2048;  // [2][32][32]
    f32x4* red = (f32x4*)smem;            // tail reuse
    bf16* Ao = (bf16*)(smem + 17408);     // tail reuse

    const int msrow = lane >> 1, msoff = (lane & 1) * 16;

    bf16x8 af[2][2];
    #pragma unroll
    for (int fm = 0; fm < 2; ++fm)
        #pragma unroll
        for (int ks = 0; ks < 2; ++ks)
            af[fm][ks] = *(const bf16x8*)(qb + (size_t)(q0 + fm * 16 + lr) * 64 + ks * 32 + lg * 8);

    *(u8x16*)&Mw[msrow * 32 + msoff] =
        *(const u8x16*)(mb + (size_t)msrow * 1024 + w * 32 + msoff);
    wait_lgkm();

    f32x4 pacc[2][4] = {};

    #pragma unroll
    for (int it = 0; it < 8; ++it) {
        const int kk0 = it << 7;
        const int cur = it & 1;
        bf16* P = Pl + cur * 32 * 136;
        const unsigned char* Mc = Mw + cur * 1024;

        if (it < 7)
            *(u8x16*)&Mw[(cur ^ 1) * 1024 + msrow * 32 + msoff] =
                *(const u8x16*)(mb + (size_t)msrow * 1024 + kk0 + 128 + w * 32 + msoff);

        bf16x8 bfr[2][2];
        #pragma unroll
        for (int fn = 0; fn < 2; ++fn)
            #pragma unroll
            for (int ks = 0; ks < 2; ++ks)
                bfr[fn][ks] = *(const bf16x8*)(kb + (size_t)(kk0 + w * 32 + fn * 16 + lr) * 64 + ks * 32 + lg * 8);

        bf16x8 vv[4];
        #pragma unroll
        for (int fn2 = 0; fn2 < 4; ++fn2)
            vv[fn2] = *(const bf16x8*)(vb + (size_t)(fn2 * 16 + lr) * 1024 + kk0 + w * 32 + lg * 8);

        f32x4 linv[2];
        #pragma unroll
        for (int fn = 0; fn < 2; ++fn) {
            const f32x4 s0 = *(const f32x4*)(c0 + kk0 + w * 32 + fn * 16 + lg * 4);
            const f32x4 s1 = *(const f32x4*)(c1 + kk0 + w * 32 + fn * 16 + lg * 4);
            #pragma unroll
            for (int r = 0; r < 4; ++r)
                linv[fn][r] = __builtin_amdgcn_rcpf(s0[r] + s1[r]);
        }

        // ---- QK^T (swapped: D[key][q]) + exp + P write (own cols) ----
        #pragma unroll
        for (int fm = 0; fm < 2; ++fm)
            #pragma unroll
            for (int fn = 0; fn < 2; ++fn) {
                f32x4 c = {0.f, 0.f, 0.f, 0.f};
                c = MFMA(bfr[fn][0], af[fm][0], c);
                c = MFMA(bfr[fn][1], af[fm][1], c);
                const int ql = fm * 16 + lr;
                const int kloc = w * 32 + fn * 16 + lg * 4;
                const unsigned int m4 = *(const unsigned int*)&Mc[ql * 32 + fn * 16 + lg * 4];
                bf16x4 pb;
                #pragma unroll
                for (int r = 0; r < 4; ++r)
                    pb[r] = f2b(((m4 >> (8 * r)) & 255u) ? 0.f : __expf(c[r]) * linv[fn][r]);
                *(bf16x4*)&P[ql * 136 + kloc] = pb;
            }

        wait_lgkm();

        // ---- PV (own k-slice) ----
        #pragma unroll
        for (int fm2 = 0; fm2 < 2; ++fm2) {
            const bf16x8 pa = *(const bf16x8*)&P[(fm2 * 16 + lr) * 136 + w * 32 + lg * 8];
            #pragma unroll
            for (int fn2 = 0; fn2 < 4; ++fn2)
                pacc[fm2][fn2] = MFMA(pa, vv[fn2], pacc[fm2][fn2]);
        }

        // ---- wave-private NT attn store: own 32 f32 cols (128B line/group) --
        {
            const int srow = lane >> 3;          // 0..7
            const int c4 = (lane & 7) * 4;       // 0..28
            #pragma unroll
            for (int rr = 0; rr < 4; ++rr) {
                const int row = srow + rr * 8;
                const uint2 pv = *(const uint2*)&P[row * 136 + w * 32 + c4];
                f32x4 o;
                o[0] = __uint_as_float(pv.x << 16);
                o[1] = __uint_as_float(pv.x & 0xffff0000u);
                o[2] = __uint_as_float(pv.y << 16);
                o[3] = __uint_as_float(pv.y & 0xffff0000u);
                __builtin_nontemporal_store(
                    o, (f32x4*)(attn_out + ((size_t)bh * 1024 + q0 + row) * 1024 + kk0 + w * 32 + c4));
            }
        }
    }

    // ---- tail: reduce 4 wave-partials (k-slices) via LDS ----
    __syncthreads();
    if (w >= 2)
        #pragma unroll
        for (int fm2 = 0; fm2 < 2; ++fm2)
            #pragma unroll
            for (int fn2 = 0; fn2 < 4; ++fn2)
                red[(fm2 * 4 + fn2) * 128 + (w - 2) * 64 + lane] = pacc[fm2][fn2];
    __syncthreads();
    if (w < 2)
        #pragma unroll
        for (int fm2 = 0; fm2 < 2; ++fm2)
            #pragma unroll
            for (int fn2 = 0; fn2 < 4; ++fn2)
                pacc[fm2][fn2] += red[(fm2 * 4 + fn2) * 128 + w * 64 + lane];
    __syncthreads();
    if (w == 1)
        #pragma unroll
        for (int fm2 = 0; fm2 < 2; ++fm2)
            #pragma unroll
            for (int fn2 = 0; fn2 < 4; ++fn2)
                red[(fm2 * 4 + fn2) * 128 + lane] = pacc[fm2][fn2];
    __syncthreads();
    if (w == 0)
        #pragma unroll
        for (int fm2 = 0; fm2 < 2; ++fm2)
            #pragma unroll
            for (int fn2 = 0; fn2 < 4; ++fn2) {
                const f32x4 s = pacc[fm2][fn2] + red[(fm2 * 4 + fn2) * 128 + lane];
                #pragma unroll
                for (int r = 0; r < 4; ++r)
                    Ao[(fm2 * 16 + lg * 4 + r) * 72 + fn2 * 16 + lr] = f2b(s[r]);
            }
    __syncthreads();
    {
        const int row = tid >> 3, c8 = (tid & 7) * 8;
        const bf16x8 v = *(const bf16x8*)&Ao[row * 72 + c8];
        *(bf16x8*)(attn_head + ((size_t)b * 1024 + q0 + row) * 1024 + h * 64 + c8) = v;
    }
}

// ---------------------------------------------------------------------------
// Output projection: BM=64, BN=128, grid (8,64) = 512 blocks (2/CU).
// Double-buffered LDS + counted vmcnt(6) (R13, kept).
// ---------------------------------------------------------------------------
__global__ __launch_bounds__(256) void k_outproj(
    const bf16* __restrict__ Ah, const bf16* __restrict__ WTo,
    const float* __restrict__ Qres, float* __restrict__ proj)
{
    __shared__ char AsB[2][8192];
    __shared__ char BsB[2][16384];

    const int tid = threadIdx.x;
    const int lane = tid & 63, w = tid >> 6;
    const int lr = lane & 15, lg = lane >> 4;
    const int wm = w >> 1, wn = w & 1;
    const int m0 = blockIdx.y * 64, n0 = blockIdx.x * 128;

    const int lrow = lane >> 3;
    const int swz8 = ((lane & 7) ^ lrow) * 8;
    const bf16* Ab = Ah  + (size_t)(m0 + w * 8 + lrow) * 1024 + swz8;
    const bf16* Bb = WTo + (size_t)(n0 + w * 8 + lrow) * 1024 + swz8;

    f32x4 acc[2][4] = {};

    {
        char* Alb = AsB[0] + w * 1024;
        char* Blb = BsB[0] + w * 1024;
        gl_lds16(Ab,         Alb);
        gl_lds16(Ab + 32768, Alb + 4096);
        #pragma unroll
        for (int i = 0; i < 4; ++i)
            gl_lds16(Bb + (size_t)i * 32768, Blb + i * 4096);
    }

    #pragma unroll
    for (int it = 0; it < 16; ++it) {
        const int cur = it & 1;

        if (it < 15) {
            const int k1 = (it + 1) * 64;
            char* Alb = AsB[cur ^ 1] + w * 1024;
            char* Blb = BsB[cur ^ 1] + w * 1024;
            gl_lds16(Ab + k1,         Alb);
            gl_lds16(Ab + 32768 + k1, Alb + 4096);
            #pragma unroll
            for (int i = 0; i < 4; ++i)
                gl_lds16(Bb + (size_t)i * 32768 + k1, Blb + i * 4096);
            __builtin_amdgcn_sched_barrier(0);
            asm volatile("s_waitcnt vmcnt(6)" ::: "memory");
        } else {
            __builtin_amdgcn_sched_barrier(0);
            asm volatile("s_waitcnt vmcnt(0)" ::: "memory");
        }
        bar_fenced();

        #pragma unroll
        for (int ks = 0; ks < 2; ++ks) {
            const int swr = ((ks * 4 + lg) ^ (lr & 7)) << 4;
            bf16x8 a[2], bb[4];
            #pragma unroll
            for (int fm = 0; fm < 2; ++fm)
                a[fm] = *(const bf16x8*)(AsB[cur] + (wm * 32 + fm * 16 + lr) * 128 + swr);
            #pragma unroll
            for (int fn = 0; fn < 4; ++fn)
                bb[fn] = *(const bf16x8*)(BsB[cur] + (wn * 64 + fn * 16 + lr) * 128 + swr);
            #pragma unroll
            for (int fm = 0; fm < 2; ++fm)
                #pragma unroll
                for (int fn = 0; fn < 4; ++fn)
                    acc[fm][fn] = MFMA(a[fm], bb[fn], acc[fm][fn]);
        }
        bar_fenced();
    }

    #pragma unroll
    for (int fm = 0; fm < 2; ++fm)
        #pragma unroll
        for (int fn = 0; fn < 4; ++fn)
            #pragma unroll
            for (int r = 0; r < 4; ++r) {
                const int m = m0 + wm * 32 + fm * 16 + lg * 4 + r;
                const int n = n0 + wn * 64 + fn * 16 + lr;
                proj[(size_t)m * 1024 + n] = acc[fm][fn][r] + Qres[(size_t)m * 1024 + n];
            }
}

// ---------------------------------------------------------------------------
// Row LayerNorm over D=1024. NT final store via ext_vector f32x4.
// ---------------------------------------------------------------------------
__global__ __launch_bounds__(256) void k_ln(
    const float* __restrict__ proj, const float* __restrict__ gam,
    const float* __restrict__ bet, float* __restrict__ out)
{
    const int row = blockIdx.x;
    const int t = threadIdx.x;
    const int lane = t & 63, w = t >> 6;
    const float4 x = *(const float4*)(proj + (size_t)row * 1024 + t * 4);
    float s = x.x + x.y + x.z + x.w;
    float ss = x.x * x.x + x.y * x.y + x.z * x.z + x.w * x.w;
    #pragma unroll
    for (int o = 1; o < 64; o <<= 1) {
        s += __shfl_xor(s, o);
        ss += __shfl_xor(ss, o);
    }
    __shared__ float rs[4], rss[4];
    if (lane == 0) { rs[w] = s; rss[w] = ss; }
    __syncthreads();
    const float S1 = rs[0] + rs[1] + rs[2] + rs[3];
    const float S2 = rss[0] + rss[1] + rss[2] + rss[3];
    const float mu = S1 * (1.0f / 1024.0f);
    const float rstd = rsqrtf(S2 * (1.0f / 1024.0f) - mu * mu + 1e-5f);
    const float4 gg = *(const float4*)(gam + t * 4);
    const float4 bb = *(const float4*)(bet + t * 4);
    f32x4 y;
    y[0] = (x.x - mu) * rstd * gg.x + bb.x;
    y[1] = (x.y - mu) * rstd * gg.y + bb.y;
    y[2] = (x.z - mu) * rstd * gg.z + bb.z;
    y[3] = (x.w - mu) * rstd * gg.w + bb.w;
    __builtin_nontemporal_store(y, (f32x4*)(out + (size_t)row * 1024 + t * 4));
}

// ---------------------------------------------------------------------------
extern "C" void kernel_launch(void* const* d_in, const int* in_sizes, int n_in,
                              void* d_out, int out_size, void* d_ws, size_t ws_size,
                              hipStream_t stream)
{
    const float* Q  = (const float*)d_in[0];
    const float* K  = (const float*)d_in[1];
    const float* V  = (const float*)d_in[2];
    const unsigned char* mask = (const unsigned char*)d_in[3];
    const float* W_Q = (const float*)d_in[4];
    const float* W_K = (const float*)d_in[5];
    const float* W_V = (const float*)d_in[6];
    const float* W_O = (const float*)d_in[7];
    const float* gam = (const float*)d_in[8];
    const float* bet = (const float*)d_in[9];

    float* out  = (float*)d_out;                     // [B,S,D]
    float* attn = out + (size_t)4 * 1024 * 1024;     // [B,H,S,S]

    bf16* wsb = (bf16*)d_ws;
    const size_t M1 = 1024 * 1024;
    bf16* WTq = wsb + 0 * M1;
    bf16* WTk = wsb + 1 * M1;
    bf16* WTv = wsb + 2 * M1;
    bf16* WTo = wsb + 3 * M1;
    bf16* qh  = wsb + 4 * M1;    // [B,H,S,64]
    bf16* kh  = wsb + 8 * M1;
    bf16* vTh = wsb + 12 * M1;   // [B,H,64,S]
    bf16* Xqb = wsb + 16 * M1;   // bf16 inputs during pre+proj
    bf16* Xkb = wsb + 20 * M1;
    bf16* Xvb = wsb + 24 * M1;
    bf16* Ah  = wsb + 16 * M1;   // overwrites Xqb (dead after k_proj)
    float* csp  = (float*)(wsb + 0 * M1);            // WTq/WTk dead after k_proj
    float* proj = (float*)(wsb + 20 * M1);           // overwrites Xkb/Xvb (dead)

    const dim3 blk(256);
    k_pre<<<dim3(1024, 7), blk, 0, stream>>>(Q, K, V, W_Q, W_K, W_V, W_O,
                                             Xqb, Xkb, Xvb, WTq, WTk, WTv, WTo);
    k_proj<<<dim3(8, 64, 3), blk, 0, stream>>>(Xqb, Xkb, Xvb, WTq, WTk, WTv, qh, kh, vTh);
    k_colsum<<<dim3(4096), blk, 0, stream>>>(qh, kh, mask, csp);
    k_attn<<<dim3(2048), blk, 0, stream>>>(qh, kh, vTh, mask, csp, attn, Ah);
    k_outproj<<<dim3(8, 64), blk, 0, stream>>>(Ah, WTo, Q, proj);
    k_ln<<<dim3(4096), blk, 0, stream>>>(proj, gam, bet, out);
}

// Round 17
// 215.796 us; speedup vs baseline: 1.2560x; 1.2560x over previous
//
#include <hip/hip_runtime.h>
#include <hip/hip_bf16.h>

// Problem constants: B=4, S=1024, D=1024, H=16, DK=DV=64
// Output 0: out [B,S,D] f32. Output 1: attn [B,H,S,S] f32 (268 MB!).
// Softmax over QUERY axis: attn[b,h,q,k] = exp(s[q,k]) / sum_q' exp(s[q',k]).
//
// R17 = R13 EXACTLY (best known, 216.07us). R16's __launch_bounds__(256,8)
// REVERTED: forcing <=64 VGPR caused scratch spills in the MFMA loops
// (216 -> 271us). 72 VGPR @ 4 waves/SIMD is the right operating point.
// Structure summary:
//  - k_pre: fused cvt (Q/K/V->bf16, q pre-scaled) + weight transpose.
//  - k_proj: BM=64xBN=128 GEMM, global_load_lds w16, XOR-swizzled LDS.
//  - k_colsum: 2-way q-split partial column sums, wave-private mask LDS,
//    barrier-free (own-wave lgkmcnt only), XCD-chunked grid.
//  - k_attn: QBLK=32, swapped-MFMA D[key][q], wave-private everything,
//    barrier-free loop, NT full-line attn stores from LDS, rcp(csp0+csp1).
//  - k_outproj: double-buffered LDS + counted vmcnt(6) K-loop.
//  - k_ln: wave-reduce LayerNorm, NT store.

typedef __bf16 bf16;
typedef bf16 bf16x4 __attribute__((ext_vector_type(4)));
typedef bf16 bf16x8 __attribute__((ext_vector_type(8)));
typedef float f32x4 __attribute__((ext_vector_type(4)));
typedef unsigned char u8x16 __attribute__((ext_vector_type(16)));

#define MFMA(a, b, c) __builtin_amdgcn_mfma_f32_16x16x32_bf16((a), (b), (c), 0, 0, 0)

__device__ __forceinline__ bf16 f2b(float x) { return (bf16)x; }

__device__ __forceinline__ void gl_lds16(const bf16* g, void* l) {
    __builtin_amdgcn_global_load_lds(
        (const __attribute__((address_space(1))) void*)g,
        (__attribute__((address_space(3))) void*)l, 16, 0, 0);
}

// Wait own-wave LDS ops only (no cross-wave barrier, no vmem drain).
__device__ __forceinline__ void wait_lgkm() {
    __builtin_amdgcn_sched_barrier(0);
    asm volatile("s_waitcnt lgkmcnt(0)" ::: "memory");
    __builtin_amdgcn_sched_barrier(0);
}

__device__ __forceinline__ void bar_fenced() {
    __builtin_amdgcn_sched_barrier(0);
    __builtin_amdgcn_s_barrier();
    __builtin_amdgcn_sched_barrier(0);
}

// ---------------------------------------------------------------------------
// Fused pre-pass. y=0..2: Q/K/V f32->bf16 (Q scaled 1/8, exact pow2).
// y=3..6: weight transpose W f32 [K][N] -> WT bf16 [N][K].
// ---------------------------------------------------------------------------
__global__ __launch_bounds__(256) void k_pre(
    const float* __restrict__ Q, const float* __restrict__ K, const float* __restrict__ V,
    const float* __restrict__ W0, const float* __restrict__ W1,
    const float* __restrict__ W2, const float* __restrict__ W3,
    bf16* __restrict__ Qb, bf16* __restrict__ Kb, bf16* __restrict__ Vb,
    bf16* __restrict__ T0, bf16* __restrict__ T1,
    bf16* __restrict__ T2, bf16* __restrict__ T3)
{
    const int z = blockIdx.y;
    __shared__ float tile[32][33];
    if (z < 3) {
        const float* src = z == 0 ? Q : z == 1 ? K : V;
        bf16* dst = z == 0 ? Qb : z == 1 ? Kb : Vb;
        const float sc = z == 0 ? 0.125f : 1.0f;
        size_t idx = ((size_t)blockIdx.x * 256 + threadIdx.x) * 8;
        const size_t stride = (size_t)gridDim.x * 2048;
        for (; idx < 4194304; idx += stride) {
            const float4 v0 = *(const float4*)(src + idx);
            const float4 v1 = *(const float4*)(src + idx + 4);
            bf16x8 o = { f2b(v0.x * sc), f2b(v0.y * sc), f2b(v0.z * sc), f2b(v0.w * sc),
                         f2b(v1.x * sc), f2b(v1.y * sc), f2b(v1.z * sc), f2b(v1.w * sc) };
            *(bf16x8*)(dst + idx) = o;
        }
    } else {
        const int zz = z - 3;
        const float* W = zz == 0 ? W0 : zz == 1 ? W1 : zz == 2 ? W2 : W3;
        bf16*        T = zz == 0 ? T0 : zz == 1 ? T1 : zz == 2 ? T2 : T3;
        const int bx = blockIdx.x & 31, by = blockIdx.x >> 5;
        const int t = threadIdx.x;
        const int r = t >> 3, c = (t & 7) * 4;
        {
            const float4 v = *(const float4*)(W + (size_t)(by * 32 + r) * 1024 + bx * 32 + c);
            tile[r][c + 0] = v.x; tile[r][c + 1] = v.y; tile[r][c + 2] = v.z; tile[r][c + 3] = v.w;
        }
        __syncthreads();
        bf16x4 o = { f2b(tile[c + 0][r]), f2b(tile[c + 1][r]), f2b(tile[c + 2][r]), f2b(tile[c + 3][r]) };
        *(bf16x4*)(T + (size_t)(bx * 32 + r) * 1024 + by * 32 + c) = o;
    }
}

// ---------------------------------------------------------------------------
// Projection GEMM: BM=64, BN=128, BK=64. grid (8, 64, 3) = 1536 blocks (6/CU).
// ---------------------------------------------------------------------------
__global__ __launch_bounds__(256) void k_proj(
    const bf16* __restrict__ Xq, const bf16* __restrict__ Xk, const bf16* __restrict__ Xv,
    const bf16* __restrict__ WTq, const bf16* __restrict__ WTk, const bf16* __restrict__ WTv,
    bf16* __restrict__ qh, bf16* __restrict__ kh, bf16* __restrict__ vTh)
{
    const int z = blockIdx.z;
    const bf16* X  = z == 0 ? Xq : z == 1 ? Xk : Xv;
    const bf16* WT = z == 0 ? WTq : z == 1 ? WTk : WTv;

    __shared__ char AsB[8192];    // [64 rows][64 k] bf16, source-swizzled
    __shared__ char BsB[16384];   // [128 rows][64 k]

    const int tid = threadIdx.x;
    const int lane = tid & 63, w = tid >> 6;
    const int lr = lane & 15, lg = lane >> 4;
    const int wm = w >> 1, wn = w & 1;
    const int m0 = blockIdx.y * 64, n0 = blockIdx.x * 128;

    const int lrow = lane >> 3;
    const int swz8 = ((lane & 7) ^ lrow) * 8;
    const bf16* Ab = X  + (size_t)(m0 + w * 8 + lrow) * 1024 + swz8;
    const bf16* Bb = WT + (size_t)(n0 + w * 8 + lrow) * 1024 + swz8;
    char* Alb = AsB + w * 1024;
    char* Blb = BsB + w * 1024;

    f32x4 acc[2][4] = {};

    for (int k0 = 0; k0 < 1024; k0 += 64) {
        gl_lds16(Ab + k0,          Alb);
        gl_lds16(Ab + 32768 + k0,  Alb + 4096);
        #pragma unroll
        for (int i = 0; i < 4; ++i)
            gl_lds16(Bb + (size_t)i * 32768 + k0, Blb + i * 4096);
        __syncthreads();
        #pragma unroll
        for (int ks = 0; ks < 2; ++ks) {
            const int swr = ((ks * 4 + lg) ^ (lr & 7)) << 4;
            bf16x8 a[2], bb[4];
            #pragma unroll
            for (int fm = 0; fm < 2; ++fm)
                a[fm] = *(const bf16x8*)(AsB + (wm * 32 + fm * 16 + lr) * 128 + swr);
            #pragma unroll
            for (int fn = 0; fn < 4; ++fn)
                bb[fn] = *(const bf16x8*)(BsB + (wn * 64 + fn * 16 + lr) * 128 + swr);
            #pragma unroll
            for (int fm = 0; fm < 2; ++fm)
                #pragma unroll
                for (int fn = 0; fn < 4; ++fn)
                    acc[fm][fn] = MFMA(a[fm], bb[fn], acc[fm][fn]);
        }
        __syncthreads();
    }

    if (z < 2) {
        bf16* dst = (z == 0) ? qh : kh;
        #pragma unroll
        for (int fm = 0; fm < 2; ++fm)
            #pragma unroll
            for (int fn = 0; fn < 4; ++fn)
                #pragma unroll
                for (int r = 0; r < 4; ++r) {
                    const int m = m0 + wm * 32 + fm * 16 + lg * 4 + r;
                    const int n = n0 + wn * 64 + fn * 16 + lr;
                    const int b = m >> 10, s = m & 1023, h = n >> 6, d = n & 63;
                    dst[(((size_t)(b * 16 + h)) * 1024 + s) * 64 + d] = f2b(acc[fm][fn][r]);
                }
    } else {
        #pragma unroll
        for (int fm = 0; fm < 2; ++fm)
            #pragma unroll
            for (int fn = 0; fn < 4; ++fn) {
                const int m = m0 + wm * 32 + fm * 16 + lg * 4;
                const int n = n0 + wn * 64 + fn * 16 + lr;
                const int b = m >> 10, s = m & 1023, h = n >> 6, d = n & 63;
                bf16x4 o = { f2b(acc[fm][fn][0]), f2b(acc[fm][fn][1]),
                             f2b(acc[fm][fn][2]), f2b(acc[fm][fn][3]) };
                *(bf16x4*)&vTh[(((size_t)(b * 16 + h)) * 64 + d) * 1024 + s] = o;
            }
    }
}

// ---------------------------------------------------------------------------
// Column softmax partial sums, 2-way q-split: csp[half][bh][k]. Grid 4096.
// ---------------------------------------------------------------------------
__global__ __launch_bounds__(256) void k_colsum(
    const bf16* __restrict__ qh, const bf16* __restrict__ kh,
    const unsigned char* __restrict__ mask, float* __restrict__ csp)
{
    const int bid = blockIdx.x;
    const int wg = (bid & 7) * 512 + (bid >> 3);   // XCD-chunked (4096 % 8 == 0)
    const int bh = wg >> 6;
    const int t6 = wg & 63;
    const int kk0 = (t6 >> 1) * 32;
    const int half = t6 & 1;
    const int qbase = half * 512;
    const int b = bh >> 4;
    const bf16* qb = qh + (size_t)bh * 65536;
    const bf16* kb = kh + (size_t)bh * 65536;
    const unsigned char* mb = mask + (size_t)b * 1048576;

    const int tid = threadIdx.x;
    const int lane = tid & 63, w = tid >> 6;
    const int lr = lane & 15, lg = lane >> 4;

    __shared__ unsigned char Ml[2][128 * 48];   // rows wave-private (w*32..+31)
    __shared__ float csum[4][32];

    const int mrow = tid >> 1, mcoff = (tid & 1) * 16;

    bf16x8 bfr[2][2];
    #pragma unroll
    for (int fn = 0; fn < 2; ++fn)
        #pragma unroll
        for (int ks = 0; ks < 2; ++ks)
            bfr[fn][ks] = *(const bf16x8*)(kb + (size_t)(kk0 + fn * 16 + lr) * 64 + ks * 32 + lg * 8);

    *(u8x16*)&Ml[0][mrow * 48 + mcoff] =
        *(const u8x16*)(mb + (size_t)(qbase + mrow) * 1024 + kk0 + mcoff);
    wait_lgkm();

    float colacc[2][4] = {};

    #pragma unroll
    for (int qt = 0; qt < 4; ++qt) {
        const int q0 = qbase + qt * 128;
        const int cur = qt & 1;
        if (qt < 3)
            *(u8x16*)&Ml[cur ^ 1][mrow * 48 + mcoff] =
                *(const u8x16*)(mb + (size_t)(q0 + 128 + mrow) * 1024 + kk0 + mcoff);

        bf16x8 a[2][2];
        #pragma unroll
        for (int fm = 0; fm < 2; ++fm) {
            const int q = q0 + w * 32 + fm * 16 + lr;
            a[fm][0] = *(const bf16x8*)(qb + (size_t)q * 64 + lg * 8);
            a[fm][1] = *(const bf16x8*)(qb + (size_t)q * 64 + 32 + lg * 8);
        }

        #pragma unroll
        for (int fm = 0; fm < 2; ++fm) {
            const int ql = w * 32 + fm * 16 + lr;
            #pragma unroll
            for (int fn = 0; fn < 2; ++fn) {
                f32x4 c = {0.f, 0.f, 0.f, 0.f};
                c = MFMA(bfr[fn][0], a[fm][0], c);
                c = MFMA(bfr[fn][1], a[fm][1], c);
                const unsigned int m4 = *(const unsigned int*)&Ml[cur][ql * 48 + fn * 16 + lg * 4];
                #pragma unroll
                for (int r = 0; r < 4; ++r)
                    colacc[fn][r] += ((m4 >> (8 * r)) & 255u) ? 0.f : __expf(c[r]);
            }
        }
        wait_lgkm();
    }

    #pragma unroll
    for (int fn = 0; fn < 2; ++fn)
        #pragma unroll
        for (int r = 0; r < 4; ++r) {
            float v = colacc[fn][r];
            v += __shfl_xor(v, 1);
            v += __shfl_xor(v, 2);
            v += __shfl_xor(v, 4);
            v += __shfl_xor(v, 8);
            if (lr == 0) csum[w][fn * 16 + lg * 4 + r] = v;
        }
    __syncthreads();
    if (tid < 32) {
        const float s = csum[0][tid] + csum[1][tid] + csum[2][tid] + csum[3][tid];
        csp[(size_t)half * 65536 + (size_t)bh * 1024 + kk0 + tid] = s;
    }
}

// ---------------------------------------------------------------------------
// Fused attn: QBLK=32, 1-D grid 2048 XCD-chunked, 4 waves, barrier-free loop.
// linv = rcp(csp[0]+csp[1]). NT attn stores from LDS (full 128B lines).
// ---------------------------------------------------------------------------
__global__ __launch_bounds__(256) void k_attn(
    const bf16* __restrict__ qh, const bf16* __restrict__ kh, const bf16* __restrict__ vTh,
    const unsigned char* __restrict__ mask, const float* __restrict__ csp,
    float* __restrict__ attn_out, bf16* __restrict__ attn_head)
{
    const int bid = blockIdx.x;
    const int wg = (bid & 7) * 256 + (bid >> 3);   // XCD-chunked
    const int bh = wg >> 5;
    const int q0 = (wg & 31) * 32;
    const int b = bh >> 4, h = bh & 15;
    const bf16* qb = qh + (size_t)bh * 65536;
    const bf16* kb = kh + (size_t)bh * 65536;
    const bf16* vb = vTh + (size_t)bh * 65536;
    const unsigned char* mb = mask + (size_t)b * 1048576 + (size_t)q0 * 1024;
    const float* c0 = csp + (size_t)bh * 1024;
    const float* c1 = csp + 65536 + (size_t)bh * 1024;

    const int tid = threadIdx.x;
    const int lane = tid & 63, w = tid >> 6;
    const int lr = lane & 15, lg = lane >> 4;

    __shared__ __align__(16) char smem[17408 + 8192];
    bf16* Pl = (bf16*)smem;
    unsigned char* Mw = (unsigned char*)(smem + 17408) + w * 2048;  // [2][32][32]
    f32x4* red = (f32x4*)smem;            // tail reuse
    bf16* Ao = (bf16*)(smem + 17408);     // tail reuse

    const int msrow = lane >> 1, msoff = (lane & 1) * 16;

    bf16x8 af[2][2];
    #pragma unroll
    for (int fm = 0; fm < 2; ++fm)
        #pragma unroll
        for (int ks = 0; ks < 2; ++ks)
            af[fm][ks] = *(const bf16x8*)(qb + (size_t)(q0 + fm * 16 + lr) * 64 + ks * 32 + lg * 8);

    *(u8x16*)&Mw[msrow * 32 + msoff] =
        *(const u8x16*)(mb + (size_t)msrow * 1024 + w * 32 + msoff);
    wait_lgkm();

    f32x4 pacc[2][4] = {};

    #pragma unroll
    for (int it = 0; it < 8; ++it) {
        const int kk0 = it << 7;
        const int cur = it & 1;
        bf16* P = Pl + cur * 32 * 136;
        const unsigned char* Mc = Mw + cur * 1024;

        if (it < 7)
            *(u8x16*)&Mw[(cur ^ 1) * 1024 + msrow * 32 + msoff] =
                *(const u8x16*)(mb + (size_t)msrow * 1024 + kk0 + 128 + w * 32 + msoff);

        bf16x8 bfr[2][2];
        #pragma unroll
        for (int fn = 0; fn < 2; ++fn)
            #pragma unroll
            for (int ks = 0; ks < 2; ++ks)
                bfr[fn][ks] = *(const bf16x8*)(kb + (size_t)(kk0 + w * 32 + fn * 16 + lr) * 64 + ks * 32 + lg * 8);

        bf16x8 vv[4];
        #pragma unroll
        for (int fn2 = 0; fn2 < 4; ++fn2)
            vv[fn2] = *(const bf16x8*)(vb + (size_t)(fn2 * 16 + lr) * 1024 + kk0 + w * 32 + lg * 8);

        f32x4 linv[2];
        #pragma unroll
        for (int fn = 0; fn < 2; ++fn) {
            const f32x4 s0 = *(const f32x4*)(c0 + kk0 + w * 32 + fn * 16 + lg * 4);
            const f32x4 s1 = *(const f32x4*)(c1 + kk0 + w * 32 + fn * 16 + lg * 4);
            #pragma unroll
            for (int r = 0; r < 4; ++r)
                linv[fn][r] = __builtin_amdgcn_rcpf(s0[r] + s1[r]);
        }

        // ---- QK^T (swapped: D[key][q]) + exp + P write (own cols) ----
        #pragma unroll
        for (int fm = 0; fm < 2; ++fm)
            #pragma unroll
            for (int fn = 0; fn < 2; ++fn) {
                f32x4 c = {0.f, 0.f, 0.f, 0.f};
                c = MFMA(bfr[fn][0], af[fm][0], c);
                c = MFMA(bfr[fn][1], af[fm][1], c);
                const int ql = fm * 16 + lr;
                const int kloc = w * 32 + fn * 16 + lg * 4;
                const unsigned int m4 = *(const unsigned int*)&Mc[ql * 32 + fn * 16 + lg * 4];
                bf16x4 pb;
                #pragma unroll
                for (int r = 0; r < 4; ++r)
                    pb[r] = f2b(((m4 >> (8 * r)) & 255u) ? 0.f : __expf(c[r]) * linv[fn][r]);
                *(bf16x4*)&P[ql * 136 + kloc] = pb;
            }

        wait_lgkm();

        // ---- PV (own k-slice) ----
        #pragma unroll
        for (int fm2 = 0; fm2 < 2; ++fm2) {
            const bf16x8 pa = *(const bf16x8*)&P[(fm2 * 16 + lr) * 136 + w * 32 + lg * 8];
            #pragma unroll
            for (int fn2 = 0; fn2 < 4; ++fn2)
                pacc[fm2][fn2] = MFMA(pa, vv[fn2], pacc[fm2][fn2]);
        }

        // ---- wave-private NT attn store: own 32 f32 cols (128B line/group) --
        {
            const int srow = lane >> 3;          // 0..7
            const int c4 = (lane & 7) * 4;       // 0..28
            #pragma unroll
            for (int rr = 0; rr < 4; ++rr) {
                const int row = srow + rr * 8;
                const uint2 pv = *(const uint2*)&P[row * 136 + w * 32 + c4];
                f32x4 o;
                o[0] = __uint_as_float(pv.x << 16);
                o[1] = __uint_as_float(pv.x & 0xffff0000u);
                o[2] = __uint_as_float(pv.y << 16);
                o[3] = __uint_as_float(pv.y & 0xffff0000u);
                __builtin_nontemporal_store(
                    o, (f32x4*)(attn_out + ((size_t)bh * 1024 + q0 + row) * 1024 + kk0 + w * 32 + c4));
            }
        }
    }

    // ---- tail: reduce 4 wave-partials (k-slices) via LDS ----
    __syncthreads();
    if (w >= 2)
        #pragma unroll
        for (int fm2 = 0; fm2 < 2; ++fm2)
            #pragma unroll
            for (int fn2 = 0; fn2 < 4; ++fn2)
                red[(fm2 * 4 + fn2) * 128 + (w - 2) * 64 + lane] = pacc[fm2][fn2];
    __syncthreads();
    if (w < 2)
        #pragma unroll
        for (int fm2 = 0; fm2 < 2; ++fm2)
            #pragma unroll
            for (int fn2 = 0; fn2 < 4; ++fn2)
                pacc[fm2][fn2] += red[(fm2 * 4 + fn2) * 128 + w * 64 + lane];
    __syncthreads();
    if (w == 1)
        #pragma unroll
        for (int fm2 = 0; fm2 < 2; ++fm2)
            #pragma unroll
            for (int fn2 = 0; fn2 < 4; ++fn2)
                red[(fm2 * 4 + fn2) * 128 + lane] = pacc[fm2][fn2];
    __syncthreads();
    if (w == 0)
        #pragma unroll
        for (int fm2 = 0; fm2 < 2; ++fm2)
            #pragma unroll
            for (int fn2 = 0; fn2 < 4; ++fn2) {
                const f32x4 s = pacc[fm2][fn2] + red[(fm2 * 4 + fn2) * 128 + lane];
                #pragma unroll
                for (int r = 0; r < 4; ++r)
                    Ao[(fm2 * 16 + lg * 4 + r) * 72 + fn2 * 16 + lr] = f2b(s[r]);
            }
    __syncthreads();
    {
        const int row = tid >> 3, c8 = (tid & 7) * 8;
        const bf16x8 v = *(const bf16x8*)&Ao[row * 72 + c8];
        *(bf16x8*)(attn_head + ((size_t)b * 1024 + q0 + row) * 1024 + h * 64 + c8) = v;
    }
}

// ---------------------------------------------------------------------------
// Output projection: BM=64, BN=128, grid (8,64) = 512 blocks (2/CU).
// Double-buffered LDS + counted vmcnt(6).
// ---------------------------------------------------------------------------
__global__ __launch_bounds__(256) void k_outproj(
    const bf16* __restrict__ Ah, const bf16* __restrict__ WTo,
    const float* __restrict__ Qres, float* __restrict__ proj)
{
    __shared__ char AsB[2][8192];
    __shared__ char BsB[2][16384];

    const int tid = threadIdx.x;
    const int lane = tid & 63, w = tid >> 6;
    const int lr = lane & 15, lg = lane >> 4;
    const int wm = w >> 1, wn = w & 1;
    const int m0 = blockIdx.y * 64, n0 = blockIdx.x * 128;

    const int lrow = lane >> 3;
    const int swz8 = ((lane & 7) ^ lrow) * 8;
    const bf16* Ab = Ah  + (size_t)(m0 + w * 8 + lrow) * 1024 + swz8;
    const bf16* Bb = WTo + (size_t)(n0 + w * 8 + lrow) * 1024 + swz8;

    f32x4 acc[2][4] = {};

    {
        char* Alb = AsB[0] + w * 1024;
        char* Blb = BsB[0] + w * 1024;
        gl_lds16(Ab,         Alb);
        gl_lds16(Ab + 32768, Alb + 4096);
        #pragma unroll
        for (int i = 0; i < 4; ++i)
            gl_lds16(Bb + (size_t)i * 32768, Blb + i * 4096);
    }

    #pragma unroll
    for (int it = 0; it < 16; ++it) {
        const int cur = it & 1;

        if (it < 15) {
            const int k1 = (it + 1) * 64;
            char* Alb = AsB[cur ^ 1] + w * 1024;
            char* Blb = BsB[cur ^ 1] + w * 1024;
            gl_lds16(Ab + k1,         Alb);
            gl_lds16(Ab + 32768 + k1, Alb + 4096);
            #pragma unroll
            for (int i = 0; i < 4; ++i)
                gl_lds16(Bb + (size_t)i * 32768 + k1, Blb + i * 4096);
            __builtin_amdgcn_sched_barrier(0);
            asm volatile("s_waitcnt vmcnt(6)" ::: "memory");
        } else {
            __builtin_amdgcn_sched_barrier(0);
            asm volatile("s_waitcnt vmcnt(0)" ::: "memory");
        }
        bar_fenced();

        #pragma unroll
        for (int ks = 0; ks < 2; ++ks) {
            const int swr = ((ks * 4 + lg) ^ (lr & 7)) << 4;
            bf16x8 a[2], bb[4];
            #pragma unroll
            for (int fm = 0; fm < 2; ++fm)
                a[fm] = *(const bf16x8*)(AsB[cur] + (wm * 32 + fm * 16 + lr) * 128 + swr);
            #pragma unroll
            for (int fn = 0; fn < 4; ++fn)
                bb[fn] = *(const bf16x8*)(BsB[cur] + (wn * 64 + fn * 16 + lr) * 128 + swr);
            #pragma unroll
            for (int fm = 0; fm < 2; ++fm)
                #pragma unroll
                for (int fn = 0; fn < 4; ++fn)
                    acc[fm][fn] = MFMA(a[fm], bb[fn], acc[fm][fn]);
        }
        bar_fenced();
    }

    #pragma unroll
    for (int fm = 0; fm < 2; ++fm)
        #pragma unroll
        for (int fn = 0; fn < 4; ++fn)
            #pragma unroll
            for (int r = 0; r < 4; ++r) {
                const int m = m0 + wm * 32 + fm * 16 + lg * 4 + r;
                const int n = n0 + wn * 64 + fn * 16 + lr;
                proj[(size_t)m * 1024 + n] = acc[fm][fn][r] + Qres[(size_t)m * 1024 + n];
            }
}

// ---------------------------------------------------------------------------
// Row LayerNorm over D=1024. NT final store via ext_vector f32x4.
// ---------------------------------------------------------------------------
__global__ __launch_bounds__(256) void k_ln(
    const float* __restrict__ proj, const float* __restrict__ gam,
    const float* __restrict__ bet, float* __restrict__ out)
{
    const int row = blockIdx.x;
    const int t = threadIdx.x;
    const int lane = t & 63, w = t >> 6;
    const float4 x = *(const float4*)(proj + (size_t)row * 1024 + t * 4);
    float s = x.x + x.y + x.z + x.w;
    float ss = x.x * x.x + x.y * x.y + x.z * x.z + x.w * x.w;
    #pragma unroll
    for (int o = 1; o < 64; o <<= 1) {
        s += __shfl_xor(s, o);
        ss += __shfl_xor(ss, o);
    }
    __shared__ float rs[4], rss[4];
    if (lane == 0) { rs[w] = s; rss[w] = ss; }
    __syncthreads();
    const float S1 = rs[0] + rs[1] + rs[2] + rs[3];
    const float S2 = rss[0] + rss[1] + rss[2] + rss[3];
    const float mu = S1 * (1.0f / 1024.0f);
    const float rstd = rsqrtf(S2 * (1.0f / 1024.0f) - mu * mu + 1e-5f);
    const float4 gg = *(const float4*)(gam + t * 4);
    const float4 bb = *(const float4*)(bet + t * 4);
    f32x4 y;
    y[0] = (x.x - mu) * rstd * gg.x + bb.x;
    y[1] = (x.y - mu) * rstd * gg.y + bb.y;
    y[2] = (x.z - mu) * rstd * gg.z + bb.z;
    y[3] = (x.w - mu) * rstd * gg.w + bb.w;
    __builtin_nontemporal_store(y, (f32x4*)(out + (size_t)row * 1024 + t * 4));
}

// ---------------------------------------------------------------------------
extern "C" void kernel_launch(void* const* d_in, const int* in_sizes, int n_in,
                              void* d_out, int out_size, void* d_ws, size_t ws_size,
                              hipStream_t stream)
{
    const float* Q  = (const float*)d_in[0];
    const float* K  = (const float*)d_in[1];
    const float* V  = (const float*)d_in[2];
    const unsigned char* mask = (const unsigned char*)d_in[3];
    const float* W_Q = (const float*)d_in[4];
    const float* W_K = (const float*)d_in[5];
    const float* W_V = (const float*)d_in[6];
    const float* W_O = (const float*)d_in[7];
    const float* gam = (const float*)d_in[8];
    const float* bet = (const float*)d_in[9];

    float* out  = (float*)d_out;                     // [B,S,D]
    float* attn = out + (size_t)4 * 1024 * 1024;     // [B,H,S,S]

    bf16* wsb = (bf16*)d_ws;
    const size_t M1 = 1024 * 1024;
    bf16* WTq = wsb + 0 * M1;
    bf16* WTk = wsb + 1 * M1;
    bf16* WTv = wsb + 2 * M1;
    bf16* WTo = wsb + 3 * M1;
    bf16* qh  = wsb + 4 * M1;    // [B,H,S,64]
    bf16* kh  = wsb + 8 * M1;
    bf16* vTh = wsb + 12 * M1;   // [B,H,64,S]
    bf16* Xqb = wsb + 16 * M1;   // bf16 inputs during pre+proj
    bf16* Xkb = wsb + 20 * M1;
    bf16* Xvb = wsb + 24 * M1;
    bf16* Ah  = wsb + 16 * M1;   // overwrites Xqb (dead after k_proj)
    float* csp  = (float*)(wsb + 0 * M1);            // WTq/WTk dead after k_proj
    float* proj = (float*)(wsb + 20 * M1);           // overwrites Xkb/Xvb (dead)

    const dim3 blk(256);
    k_pre<<<dim3(1024, 7), blk, 0, stream>>>(Q, K, V, W_Q, W_K, W_V, W_O,
                                             Xqb, Xkb, Xvb, WTq, WTk, WTv, WTo);
    k_proj<<<dim3(8, 64, 3), blk, 0, stream>>>(Xqb, Xkb, Xvb, WTq, WTk, WTv, qh, kh, vTh);
    k_colsum<<<dim3(4096), blk, 0, stream>>>(qh, kh, mask, csp);
    k_attn<<<dim3(2048), blk, 0, stream>>>(qh, kh, vTh, mask, csp, attn, Ah);
    k_outproj<<<dim3(8, 64), blk, 0, stream>>>(Ah, WTo, Q, proj);
    k_ln<<<dim3(4096), blk, 0, stream>>>(proj, gam, bet, out);
}